// Round 6
// baseline (3435.683 us; speedup 1.0000x reference)
//
#include <hip/hip_runtime.h>
#include <hip/hip_bf16.h>

#define B_  64
#define S_  128
#define WP_ 18
#define K_  3
#define E_  128
#define H_  256
#define L_  4
#define T_  50

typedef __hip_bfloat16 bf16;
typedef float f32x2 __attribute__((ext_vector_type(2)));

__device__ __forceinline__ float b2f(bf16 x) { return __bfloat162float(x); }
__device__ __forceinline__ bf16  f2b(float x) { return __float2bfloat16(x); }

__device__ __forceinline__ float fast_sigmoid(float x) {
    return 1.f / (1.f + __expf(-x));
}
__device__ __forceinline__ float fast_tanh(float x) {
    float a = fminf(fmaxf(2.f * x, -30.f), 30.f);
    float e = __expf(a);
    return (e - 1.f) / (e + 1.f);
}

// ---------------------------------------------------------------- transpose (f32 -> bf16)
__global__ void k_transpose(const float* __restrict__ src, bf16* __restrict__ dst,
                            int R, int C) {
    int i = blockIdx.x * 256 + threadIdx.x;
    if (i >= R * C) return;
    int r = i / C, c = i % C;
    dst[c * R + r] = f2b(src[i]);
}

// ---------------------------------------------------------------- pack Whh to fp8 (e4m3, OCP)
// column col (0..1023) = output unit j; weight k (0..255).
// byte layout: dst[((jb*16 + kb)*64 + lane)*16 + (k&15)], jb=col>>6, lane=col&63, kb=k>>4
// -> a wave's (64 lanes = 64 consecutive columns) kb-th uint4 load is 1KB coalesced,
//    bytes 0..15 of each lane's uint4 = weights k=kb*16..kb*16+15 of its column.
__global__ void k_pack_whh_fp8(const float* __restrict__ src, unsigned char* __restrict__ dst) {
    int idx = blockIdx.x * 256 + threadIdx.x;    // pair index over 1024*128
    if (idx >= 1024 * 128) return;
    int col = idx >> 7, kp = idx & 127;
    int k = kp * 2;
    float a = src[col * 256 + k];
    float b = src[col * 256 + k + 1];
    int w = __builtin_amdgcn_cvt_pk_fp8_f32(a, b, 0, false);   // byte0=fp8(a), byte1=fp8(b)
    int jb = col >> 6, lane = col & 63, kb = k >> 4;
    *(unsigned short*)(dst + ((((jb * 16 + kb) * 64 + lane) << 4) + (k & 14))) =
        (unsigned short)(w & 0xffff);
}

// ---------------------------------------------------------------- char CNN
__global__ void k_charcnn(const int* __restrict__ char_ids,
                          const float* __restrict__ char_emb,
                          const float* __restrict__ cnn_w,
                          const float* __restrict__ cnn_b,
                          float* __restrict__ out_char) {
    const int CE_S = 132;
    const int W_S  = 388;
    __shared__ float ce[WP_ * 132];
    __shared__ float w[L_ * 388];
    __shared__ float bias[L_];
    int idx = blockIdx.x;            // b*S + s
    int t   = threadIdx.x;           // 0..63
    const int* ids = char_ids + idx * WP_;
    for (int i = t; i < WP_ * E_; i += 64) {
        int r = i >> 7, e = i & 127;
        ce[r * CE_S + e] = char_emb[ids[r] * E_ + e];
    }
    for (int i = t; i < L_ * K_ * E_; i += 64) {
        int r = i / (K_ * E_), e = i % (K_ * E_);
        w[r * W_S + e] = cnn_w[i];
    }
    if (t < L_) bias[t] = cnn_b[t];
    __syncthreads();
    int pos = t >> 2, c = t & 3;     // 16 positions x 4 channels
    float acc = 0.f;
    const float* wr = &w[c * W_S];
    #pragma unroll
    for (int i = 0; i < K_; ++i) {
        const float* cr = &ce[(pos + i) * CE_S];
        #pragma unroll 8
        for (int e = 0; e < E_; ++e) acc = fmaf(cr[e], wr[i * E_ + e], acc);
    }
    acc += bias[c];
    #pragma unroll
    for (int off = 4; off < 64; off <<= 1) acc = fmaxf(acc, __shfl_xor(acc, off));
    if (t < L_) out_char[idx * L_ + t] = acc;
}

// ---------------------------------------------------------------- input proj
// ig[s*B+b, j] = b[j] + sum_k we[b,s,k] * WihT[k, j]   (both directions)
__global__ void k_input_proj(const int* __restrict__ word_ids,
                             const float* __restrict__ word_emb,
                             const bf16* __restrict__ wihT_f, const float* __restrict__ b_f,
                             const bf16* __restrict__ wihT_b, const float* __restrict__ b_b,
                             bf16* __restrict__ ig_f, bf16* __restrict__ ig_b) {
    int dir = blockIdx.y;
    const bf16* wihT = dir ? wihT_b : wihT_f;
    const float* bb  = dir ? b_b    : b_f;
    bf16* ig         = dir ? ig_b   : ig_f;
    __shared__ float x[8][128];
    int t  = threadIdx.x;            // 0..255
    int r0 = blockIdx.x * 8;         // 8 rows (s*B+b) per block
    for (int i = t; i < 8 * 128; i += 256) {
        int rr = i >> 7, e = i & 127;
        int r = r0 + rr;
        int s = r >> 6, b = r & 63;
        int wid = word_ids[b * S_ + s];
        x[rr][e] = word_emb[(size_t)wid * E_ + e];
    }
    __syncthreads();
    int j = t;
    float acc[4][8];
    #pragma unroll
    for (int cj = 0; cj < 4; ++cj) {
        float bv = bb[j + cj * 256];
        #pragma unroll
        for (int rr = 0; rr < 8; ++rr) acc[cj][rr] = bv;
    }
    for (int k = 0; k < 128; ++k) {
        float wv[4];
        #pragma unroll
        for (int cj = 0; cj < 4; ++cj) wv[cj] = b2f(wihT[k * 1024 + j + cj * 256]);
        #pragma unroll
        for (int rr = 0; rr < 8; ++rr) {
            float xv = x[rr][k];
            #pragma unroll
            for (int cj = 0; cj < 4; ++cj) acc[cj][rr] = fmaf(xv, wv[cj], acc[cj][rr]);
        }
    }
    #pragma unroll
    for (int cj = 0; cj < 4; ++cj)
        #pragma unroll
        for (int rr = 0; rr < 8; ++rr)
            ig[(size_t)(r0 + rr) * 1024 + j + cj * 256] = f2b(acc[cj][rr]);
}

// ---------------------------------------------------------------- recurrence
// Round-3 structure: one block per (batch, direction); thread t owns column j=t.
// Whh now fp8: each wave's kb-th uint4 load = 16 fp8 weights/lane, coalesced 1KB.
// Decode via v_cvt_pk_f32_fp8 (2 weights/inst), h broadcast-read from LDS.
__global__ __launch_bounds__(1024) void k_lstm_rec(
        const bf16* __restrict__ ig_f, const bf16* __restrict__ ig_b,
        const uint4* __restrict__ wp_f, const uint4* __restrict__ wp_b,
        float* __restrict__ hf, float* __restrict__ hb) {
    int b   = blockIdx.x & 63;
    int dir = blockIdx.x >> 6;
    const bf16* ig  = dir ? ig_b : ig_f;
    const uint4* wp = dir ? wp_b : wp_f;
    float* hs       = dir ? hb   : hf;
    __shared__ __align__(16) float h[256];
    __shared__ float zbuf[1024];
    int t = threadIdx.x;
    int jb = t >> 6, lane = t & 63;
    const uint4* wrow = wp + (jb * 16 * 64 + lane);   // advance by 64 per kb
    if (t < 256) h[t] = 0.f;
    float c = 0.f;
    __syncthreads();
    for (int step = 0; step < S_; ++step) {
        int s = dir ? (S_ - 1 - step) : step;
        float z = b2f(ig[((size_t)s * B_ + b) * 1024 + t]);
        #pragma unroll
        for (int kb = 0; kb < 16; ++kb) {
            uint4 wv = wrow[kb * 64];
            const float4* hp = (const float4*)&h[kb * 16];
            float4 h0 = hp[0], h1 = hp[1], h2 = hp[2], h3 = hp[3];
            f32x2 f;
            f = __builtin_amdgcn_cvt_pk_f32_fp8(wv.x, false);
            z = fmaf(f.x, h0.x, z); z = fmaf(f.y, h0.y, z);
            f = __builtin_amdgcn_cvt_pk_f32_fp8(wv.x, true);
            z = fmaf(f.x, h0.z, z); z = fmaf(f.y, h0.w, z);
            f = __builtin_amdgcn_cvt_pk_f32_fp8(wv.y, false);
            z = fmaf(f.x, h1.x, z); z = fmaf(f.y, h1.y, z);
            f = __builtin_amdgcn_cvt_pk_f32_fp8(wv.y, true);
            z = fmaf(f.x, h1.z, z); z = fmaf(f.y, h1.w, z);
            f = __builtin_amdgcn_cvt_pk_f32_fp8(wv.z, false);
            z = fmaf(f.x, h2.x, z); z = fmaf(f.y, h2.y, z);
            f = __builtin_amdgcn_cvt_pk_f32_fp8(wv.z, true);
            z = fmaf(f.x, h2.z, z); z = fmaf(f.y, h2.w, z);
            f = __builtin_amdgcn_cvt_pk_f32_fp8(wv.w, false);
            z = fmaf(f.x, h3.x, z); z = fmaf(f.y, h3.y, z);
            f = __builtin_amdgcn_cvt_pk_f32_fp8(wv.w, true);
            z = fmaf(f.x, h3.z, z); z = fmaf(f.y, h3.w, z);
        }
        zbuf[t] = z;
        __syncthreads();
        if (t < 256) {
            float zi = zbuf[t], zf = zbuf[t + 256], zg = zbuf[t + 512], zo = zbuf[t + 768];
            float si = fast_sigmoid(zi);
            float sf = fast_sigmoid(zf);
            float so = fast_sigmoid(zo);
            float tg = fast_tanh(zg);
            c = sf * c + si * tg;
            float hn = so * fast_tanh(c);
            h[t] = hn;
            hs[((size_t)s * B_ + b) * 256 + t] = hn;
        }
        __syncthreads();
    }
}

// ---------------------------------------------------------------- tag linear
__global__ void k_tag_linear(const float* __restrict__ hf, const float* __restrict__ hb,
                             const float* __restrict__ out_w, const float* __restrict__ out_b,
                             float* __restrict__ tag) {
    int bs = blockIdx.x;             // b*S + s
    int b = bs >> 7, s = bs & 127;
    __shared__ float hv[512];
    int t = threadIdx.x;             // 0..63
    const float* hfr = hf + ((size_t)s * B_ + b) * 256;
    const float* hbr = hb + ((size_t)s * B_ + b) * 256;
    for (int i = t; i < 256; i += 64) { hv[i] = hfr[i]; hv[256 + i] = hbr[i]; }
    __syncthreads();
    if (t < T_) {
        float acc = out_b[t];
        #pragma unroll 8
        for (int k = 0; k < 512; ++k) acc = fmaf(hv[k], out_w[t * 512 + k], acc);
        tag[((size_t)b * T_ + t) * S_ + s] = acc;
    }
}

// ---------------------------------------------------------------- log_softmax over S (axis=1)
__global__ void k_log_softmax(const float* __restrict__ tag, float* __restrict__ out) {
    int wid  = (blockIdx.x * 256 + threadIdx.x) >> 6;   // one wave per (b,t)
    int lane = threadIdx.x & 63;
    if (wid >= B_ * T_) return;
    int b = wid / T_, t = wid % T_;
    const float* row = tag + (size_t)wid * S_;
    float v0 = row[lane], v1 = row[lane + 64];
    float m = fmaxf(v0, v1);
    #pragma unroll
    for (int off = 32; off; off >>= 1) m = fmaxf(m, __shfl_xor(m, off));
    float e = expf(v0 - m) + expf(v1 - m);
    #pragma unroll
    for (int off = 32; off; off >>= 1) e += __shfl_xor(e, off);
    float lse = m + logf(e);
    out[((size_t)b * S_ + lane)      * T_ + t] = v0 - lse;
    out[((size_t)b * S_ + lane + 64) * T_ + t] = v1 - lse;
}

// ---------------------------------------------------------------- launch
extern "C" void kernel_launch(void* const* d_in, const int* in_sizes, int n_in,
                              void* d_out, int out_size, void* d_ws, size_t ws_size,
                              hipStream_t stream) {
    const int*   char_ids = (const int*)d_in[0];
    const int*   word_ids = (const int*)d_in[1];
    const float* char_emb = (const float*)d_in[2];
    const float* word_emb = (const float*)d_in[3];
    const float* cnn_w    = (const float*)d_in[4];
    const float* cnn_b    = (const float*)d_in[5];
    const float* wih_f    = (const float*)d_in[6];
    const float* whh_f    = (const float*)d_in[7];
    const float* b_f      = (const float*)d_in[8];
    const float* wih_b    = (const float*)d_in[9];
    const float* whh_b    = (const float*)d_in[10];
    const float* b_b      = (const float*)d_in[11];
    const float* out_w    = (const float*)d_in[12];
    const float* out_b    = (const float*)d_in[13];
    float* out = (float*)d_out;
    char* ws   = (char*)d_ws;

    size_t o = 0;
    bf16* wihT_f = (bf16*)(ws + o); o += (size_t)128 * 1024 * 2;
    bf16* wihT_b = (bf16*)(ws + o); o += (size_t)128 * 1024 * 2;
    unsigned char* wp_f = (unsigned char*)(ws + o); o += (size_t)1024 * 256;
    unsigned char* wp_b = (unsigned char*)(ws + o); o += (size_t)1024 * 256;
    bf16* ig_f   = (bf16*)(ws + o); o += (size_t)S_ * B_ * 1024 * 2;
    bf16* ig_b   = (bf16*)(ws + o); o += (size_t)S_ * B_ * 1024 * 2;
    float* hf    = (float*)(ws + o); o += (size_t)S_ * B_ * 256 * 4;
    float* hb    = (float*)(ws + o); o += (size_t)S_ * B_ * 256 * 4;
    float* tag   = (float*)(ws + o); o += (size_t)B_ * T_ * S_ * 4;

    k_transpose<<<512, 256, 0, stream>>>(wih_f, wihT_f, 1024, 128);
    k_transpose<<<512, 256, 0, stream>>>(wih_b, wihT_b, 1024, 128);
    k_pack_whh_fp8<<<512, 256, 0, stream>>>(whh_f, wp_f);
    k_pack_whh_fp8<<<512, 256, 0, stream>>>(whh_b, wp_b);
    k_input_proj<<<dim3(1024, 2), 256, 0, stream>>>(word_ids, word_emb,
                                                    wihT_f, b_f, wihT_b, b_b, ig_f, ig_b);
    k_charcnn<<<B_ * S_, 64, 0, stream>>>(char_ids, char_emb, cnn_w, cnn_b,
                                          out + (size_t)B_ * S_ * T_);
    k_lstm_rec<<<128, 1024, 0, stream>>>(ig_f, ig_b, (const uint4*)wp_f, (const uint4*)wp_b,
                                         hf, hb);
    k_tag_linear<<<B_ * S_, 64, 0, stream>>>(hf, hb, out_w, out_b, tag);
    k_log_softmax<<<(B_ * T_ + 3) / 4, 256, 0, stream>>>(tag, out);
}

// Round 7
// 860.727 us; speedup vs baseline: 3.9916x; 3.9916x over previous
//
#include <hip/hip_runtime.h>
#include <hip/hip_bf16.h>

#define B_  64
#define S_  128
#define WP_ 18
#define K_  3
#define E_  128
#define H_  256
#define L_  4
#define T_  50

typedef __hip_bfloat16 bf16;

__device__ __forceinline__ float b2f(bf16 x) { return __bfloat162float(x); }
__device__ __forceinline__ bf16  f2b(float x) { return __float2bfloat16(x); }

__device__ __forceinline__ float fast_sigmoid(float x) {
    return 1.f / (1.f + __expf(-x));
}
__device__ __forceinline__ float fast_tanh(float x) {
    float a = fminf(fmaxf(2.f * x, -30.f), 30.f);
    float e = __expf(a);
    return (e - 1.f) / (e + 1.f);
}

// ---------------------------------------------------------------- transpose (f32 -> bf16)
__global__ void k_transpose(const float* __restrict__ src, bf16* __restrict__ dst,
                            int R, int C) {
    int i = blockIdx.x * 256 + threadIdx.x;
    if (i >= R * C) return;
    int r = i / C, c = i % C;
    dst[c * R + r] = f2b(src[i]);
}

// ---------------------------------------------------------------- pack Whh (round-3 proven)
// dst[((jb*32 + kb)*64 + lane)*8 + e] = src[(jb*64+lane)*256 + kb*8 + e]  (bf16)
__global__ void k_pack_whh(const float* __restrict__ src, bf16* __restrict__ dst) {
    int i = blockIdx.x * 256 + threadIdx.x;   // over 1024*256
    if (i >= 1024 * 256) return;
    int j = i >> 8, k = i & 255;
    int jb = j >> 6, lane = j & 63, kb = k >> 3, e = k & 7;
    dst[(((jb * 32 + kb) * 64 + lane) << 3) + e] = f2b(src[i]);
}

// ---------------------------------------------------------------- char CNN
__global__ void k_charcnn(const int* __restrict__ char_ids,
                          const float* __restrict__ char_emb,
                          const float* __restrict__ cnn_w,
                          const float* __restrict__ cnn_b,
                          float* __restrict__ out_char) {
    const int CE_S = 132;
    const int W_S  = 388;
    __shared__ float ce[WP_ * 132];
    __shared__ float w[L_ * 388];
    __shared__ float bias[L_];
    int idx = blockIdx.x;            // b*S + s
    int t   = threadIdx.x;           // 0..63
    const int* ids = char_ids + idx * WP_;
    for (int i = t; i < WP_ * E_; i += 64) {
        int r = i >> 7, e = i & 127;
        ce[r * CE_S + e] = char_emb[ids[r] * E_ + e];
    }
    for (int i = t; i < L_ * K_ * E_; i += 64) {
        int r = i / (K_ * E_), e = i % (K_ * E_);
        w[r * W_S + e] = cnn_w[i];
    }
    if (t < L_) bias[t] = cnn_b[t];
    __syncthreads();
    int pos = t >> 2, c = t & 3;     // 16 positions x 4 channels
    float acc = 0.f;
    const float* wr = &w[c * W_S];
    #pragma unroll
    for (int i = 0; i < K_; ++i) {
        const float* cr = &ce[(pos + i) * CE_S];
        #pragma unroll 8
        for (int e = 0; e < E_; ++e) acc = fmaf(cr[e], wr[i * E_ + e], acc);
    }
    acc += bias[c];
    #pragma unroll
    for (int off = 4; off < 64; off <<= 1) acc = fmaxf(acc, __shfl_xor(acc, off));
    if (t < L_) out_char[idx * L_ + t] = acc;
}

// ---------------------------------------------------------------- input proj
__global__ void k_input_proj(const int* __restrict__ word_ids,
                             const float* __restrict__ word_emb,
                             const bf16* __restrict__ wihT_f, const float* __restrict__ b_f,
                             const bf16* __restrict__ wihT_b, const float* __restrict__ b_b,
                             bf16* __restrict__ ig_f, bf16* __restrict__ ig_b) {
    int dir = blockIdx.y;
    const bf16* wihT = dir ? wihT_b : wihT_f;
    const float* bb  = dir ? b_b    : b_f;
    bf16* ig         = dir ? ig_b   : ig_f;
    __shared__ float x[8][128];
    int t  = threadIdx.x;            // 0..255
    int r0 = blockIdx.x * 8;         // 8 rows (s*B+b) per block
    for (int i = t; i < 8 * 128; i += 256) {
        int rr = i >> 7, e = i & 127;
        int r = r0 + rr;
        int s = r >> 6, b = r & 63;
        int wid = word_ids[b * S_ + s];
        x[rr][e] = word_emb[(size_t)wid * E_ + e];
    }
    __syncthreads();
    int j = t;
    float acc[4][8];
    #pragma unroll
    for (int cj = 0; cj < 4; ++cj) {
        float bv = bb[j + cj * 256];
        #pragma unroll
        for (int rr = 0; rr < 8; ++rr) acc[cj][rr] = bv;
    }
    for (int k = 0; k < 128; ++k) {
        float wv[4];
        #pragma unroll
        for (int cj = 0; cj < 4; ++cj) wv[cj] = b2f(wihT[k * 1024 + j + cj * 256]);
        #pragma unroll
        for (int rr = 0; rr < 8; ++rr) {
            float xv = x[rr][k];
            #pragma unroll
            for (int cj = 0; cj < 4; ++cj) acc[cj][rr] = fmaf(xv, wv[cj], acc[cj][rr]);
        }
    }
    #pragma unroll
    for (int cj = 0; cj < 4; ++cj)
        #pragma unroll
        for (int rr = 0; rr < 8; ++rr)
            ig[(size_t)(r0 + rr) * 1024 + j + cj * 256] = f2b(acc[cj][rr]);
}

// ---------------------------------------------------------------- 8-MAC inner body (round-3 proven)
__device__ __forceinline__ void fma8(uint4 wv, const float* __restrict__ hk, float& z) {
    float4 h0 = *(const float4*)hk;
    float4 h1 = *(const float4*)(hk + 4);
    z = fmaf(__uint_as_float(wv.x << 16),          h0.x, z);
    z = fmaf(__uint_as_float(wv.x & 0xffff0000u),  h0.y, z);
    z = fmaf(__uint_as_float(wv.y << 16),          h0.z, z);
    z = fmaf(__uint_as_float(wv.y & 0xffff0000u),  h0.w, z);
    z = fmaf(__uint_as_float(wv.z << 16),          h1.x, z);
    z = fmaf(__uint_as_float(wv.z & 0xffff0000u),  h1.y, z);
    z = fmaf(__uint_as_float(wv.w << 16),          h1.z, z);
    z = fmaf(__uint_as_float(wv.w & 0xffff0000u),  h1.w, z);
}

// ---------------------------------------------------------------- recurrence
// Round-3 structure: one block per (batch, direction); thread t owns column j=t.
// NEW: waves 0..3 (columns 0..255) read their 128KB weight slice from LDS
// (preloaded once, identical packed layout); waves 4..15 stream from L2.
// Per-step L2 weight traffic drops 512KB -> 384KB. Plus ig prefetch (round-5 proven).
__global__ __launch_bounds__(1024) void k_lstm_rec(
        const bf16* __restrict__ ig_f, const bf16* __restrict__ ig_b,
        const uint4* __restrict__ wp_f, const uint4* __restrict__ wp_b,
        float* __restrict__ hf, float* __restrict__ hb) {
    __shared__ uint4 wlds[8192];            // 128 KiB: weight slices jb=0..3
    __shared__ __align__(16) float h[256];
    __shared__ float zbuf[1024];

    int b   = blockIdx.x & 63;
    int dir = blockIdx.x >> 6;
    const bf16* ig  = dir ? ig_b : ig_f;
    const uint4* wp = dir ? wp_b : wp_f;
    float* hs       = dir ? hb   : hf;

    int t = threadIdx.x;
    int jb = t >> 6, lane = t & 63;

    // one-time preload of first 4 jb-slices (first 8192 uint4 of wp), coalesced
    for (int u = t; u < 8192; u += 1024) wlds[u] = wp[u];
    if (t < 256) h[t] = 0.f;
    float c = 0.f;
    __syncthreads();

    const uint4* wl = &wlds[jb * 2048 + lane];          // LDS path (jb<4)
    const uint4* wg = wp + (jb * 2048 + lane);          // global path

    int s0 = dir ? (S_ - 1) : 0;
    unsigned short igu = *(const unsigned short*)&ig[((size_t)s0 * B_ + b) * 1024 + t];

    for (int step = 0; step < S_; ++step) {
        int s = dir ? (S_ - 1 - step) : step;
        float z = __uint_as_float((unsigned int)igu << 16);
        if (jb < 4) {
            #pragma unroll 8
            for (int kb = 0; kb < 32; ++kb) fma8(wl[kb * 64], &h[kb * 8], z);
        } else {
            #pragma unroll 8
            for (int kb = 0; kb < 32; ++kb) fma8(wg[kb * 64], &h[kb * 8], z);
        }
        // prefetch next step's ig element (hides L2 latency under gates+sync)
        if (step + 1 < S_) {
            int sn = dir ? (S_ - 2 - step) : (step + 1);
            igu = *(const unsigned short*)&ig[((size_t)sn * B_ + b) * 1024 + t];
        }
        zbuf[t] = z;
        __syncthreads();
        if (t < 256) {
            float zi = zbuf[t], zf = zbuf[t + 256], zg = zbuf[t + 512], zo = zbuf[t + 768];
            float si = fast_sigmoid(zi);
            float sf = fast_sigmoid(zf);
            float so = fast_sigmoid(zo);
            float tg = fast_tanh(zg);
            c = sf * c + si * tg;
            float hn = so * fast_tanh(c);
            h[t] = hn;
            hs[((size_t)s * B_ + b) * 256 + t] = hn;
        }
        __syncthreads();
    }
}

// ---------------------------------------------------------------- tag linear
__global__ void k_tag_linear(const float* __restrict__ hf, const float* __restrict__ hb,
                             const float* __restrict__ out_w, const float* __restrict__ out_b,
                             float* __restrict__ tag) {
    int bs = blockIdx.x;             // b*S + s
    int b = bs >> 7, s = bs & 127;
    __shared__ float hv[512];
    int t = threadIdx.x;             // 0..63
    const float* hfr = hf + ((size_t)s * B_ + b) * 256;
    const float* hbr = hb + ((size_t)s * B_ + b) * 256;
    for (int i = t; i < 256; i += 64) { hv[i] = hfr[i]; hv[256 + i] = hbr[i]; }
    __syncthreads();
    if (t < T_) {
        float acc = out_b[t];
        #pragma unroll 8
        for (int k = 0; k < 512; ++k) acc = fmaf(hv[k], out_w[t * 512 + k], acc);
        tag[((size_t)b * T_ + t) * S_ + s] = acc;
    }
}

// ---------------------------------------------------------------- log_softmax over S (axis=1)
__global__ void k_log_softmax(const float* __restrict__ tag, float* __restrict__ out) {
    int wid  = (blockIdx.x * 256 + threadIdx.x) >> 6;   // one wave per (b,t)
    int lane = threadIdx.x & 63;
    if (wid >= B_ * T_) return;
    int b = wid / T_, t = wid % T_;
    const float* row = tag + (size_t)wid * S_;
    float v0 = row[lane], v1 = row[lane + 64];
    float m = fmaxf(v0, v1);
    #pragma unroll
    for (int off = 32; off; off >>= 1) m = fmaxf(m, __shfl_xor(m, off));
    float e = expf(v0 - m) + expf(v1 - m);
    #pragma unroll
    for (int off = 32; off; off >>= 1) e += __shfl_xor(e, off);
    float lse = m + logf(e);
    out[((size_t)b * S_ + lane)      * T_ + t] = v0 - lse;
    out[((size_t)b * S_ + lane + 64) * T_ + t] = v1 - lse;
}

// ---------------------------------------------------------------- launch
extern "C" void kernel_launch(void* const* d_in, const int* in_sizes, int n_in,
                              void* d_out, int out_size, void* d_ws, size_t ws_size,
                              hipStream_t stream) {
    const int*   char_ids = (const int*)d_in[0];
    const int*   word_ids = (const int*)d_in[1];
    const float* char_emb = (const float*)d_in[2];
    const float* word_emb = (const float*)d_in[3];
    const float* cnn_w    = (const float*)d_in[4];
    const float* cnn_b    = (const float*)d_in[5];
    const float* wih_f    = (const float*)d_in[6];
    const float* whh_f    = (const float*)d_in[7];
    const float* b_f      = (const float*)d_in[8];
    const float* wih_b    = (const float*)d_in[9];
    const float* whh_b    = (const float*)d_in[10];
    const float* b_b      = (const float*)d_in[11];
    const float* out_w    = (const float*)d_in[12];
    const float* out_b    = (const float*)d_in[13];
    float* out = (float*)d_out;
    char* ws   = (char*)d_ws;

    size_t o = 0;
    bf16* wihT_f = (bf16*)(ws + o); o += (size_t)128 * 1024 * 2;
    bf16* wihT_b = (bf16*)(ws + o); o += (size_t)128 * 1024 * 2;
    bf16* wp_f   = (bf16*)(ws + o); o += (size_t)256 * 1024 * 2;
    bf16* wp_b   = (bf16*)(ws + o); o += (size_t)256 * 1024 * 2;
    bf16* ig_f   = (bf16*)(ws + o); o += (size_t)S_ * B_ * 1024 * 2;
    bf16* ig_b   = (bf16*)(ws + o); o += (size_t)S_ * B_ * 1024 * 2;
    float* hf    = (float*)(ws + o); o += (size_t)S_ * B_ * 256 * 4;
    float* hb    = (float*)(ws + o); o += (size_t)S_ * B_ * 256 * 4;
    float* tag   = (float*)(ws + o); o += (size_t)B_ * T_ * S_ * 4;

    k_transpose<<<512, 256, 0, stream>>>(wih_f, wihT_f, 1024, 128);
    k_transpose<<<512, 256, 0, stream>>>(wih_b, wihT_b, 1024, 128);
    k_pack_whh<<<1024, 256, 0, stream>>>(whh_f, wp_f);
    k_pack_whh<<<1024, 256, 0, stream>>>(whh_b, wp_b);
    k_input_proj<<<dim3(1024, 2), 256, 0, stream>>>(word_ids, word_emb,
                                                    wihT_f, b_f, wihT_b, b_b, ig_f, ig_b);
    k_charcnn<<<B_ * S_, 64, 0, stream>>>(char_ids, char_emb, cnn_w, cnn_b,
                                          out + (size_t)B_ * S_ * T_);
    k_lstm_rec<<<128, 1024, 0, stream>>>(ig_f, ig_b, (const uint4*)wp_f, (const uint4*)wp_b,
                                         hf, hb);
    k_tag_linear<<<B_ * S_, 64, 0, stream>>>(hf, hb, out_w, out_b, tag);
    k_log_softmax<<<(B_ * T_ + 3) / 4, 256, 0, stream>>>(tag, out);
}

// Round 9
// 737.191 us; speedup vs baseline: 4.6605x; 1.1676x over previous
//
#include <hip/hip_runtime.h>
#include <hip/hip_bf16.h>

#define B_  64
#define S_  128
#define WP_ 18
#define K_  3
#define E_  128
#define H_  256
#define L_  4
#define T_  50

typedef __hip_bfloat16 bf16;

__device__ __forceinline__ float b2f(bf16 x) { return __bfloat162float(x); }
__device__ __forceinline__ bf16  f2b(float x) { return __float2bfloat16(x); }

__device__ __forceinline__ float fast_sigmoid(float x) {
    return 1.f / (1.f + __expf(-x));
}
__device__ __forceinline__ float fast_tanh(float x) {
    float a = fminf(fmaxf(2.f * x, -30.f), 30.f);
    float e = __expf(a);
    return (e - 1.f) / (e + 1.f);
}

// v_dot2_f32_bf16: z += lo(w)*lo(h) + hi(w)*hi(h), all ops one VALU inst
#define DOT2(z, w, h) asm("v_dot2_f32_bf16 %0, %1, %2, %0" : "+v"(z) : "v"(w), "v"(h))

// ---------------------------------------------------------------- transpose (f32 -> bf16)
__global__ void k_transpose(const float* __restrict__ src, bf16* __restrict__ dst,
                            int R, int C) {
    int i = blockIdx.x * 256 + threadIdx.x;
    if (i >= R * C) return;
    int r = i / C, c = i % C;
    dst[c * R + r] = f2b(src[i]);
}

// ---------------------------------------------------------------- pack Whh for k-split layout
// thread (i,p) [t=i*4+p] needs w[col=g*256+i][k=64p..64p+63] as 8 uint4 (m=g*8+kk).
// dst uint4 index = m*1024 + t; bf16 element e = k&7.
__global__ void k_pack_whh(const float* __restrict__ src, bf16* __restrict__ dst) {
    int idx = blockIdx.x * 256 + threadIdx.x;   // over 1024*256
    if (idx >= 1024 * 256) return;
    int col = idx >> 8, k = idx & 255;
    int g = col >> 8, i = col & 255;
    int p = k >> 6, kk = (k >> 3) & 7, e = k & 7;
    int t = i * 4 + p, m = g * 8 + kk;
    dst[((size_t)(m * 1024 + t) << 3) + e] = f2b(src[col * 256 + k]);
}

// ---------------------------------------------------------------- char CNN
__global__ void k_charcnn(const int* __restrict__ char_ids,
                          const float* __restrict__ char_emb,
                          const float* __restrict__ cnn_w,
                          const float* __restrict__ cnn_b,
                          float* __restrict__ out_char) {
    const int CE_S = 132;
    const int W_S  = 388;
    __shared__ float ce[WP_ * 132];
    __shared__ float w[L_ * 388];
    __shared__ float bias[L_];
    int idx = blockIdx.x;            // b*S + s
    int t   = threadIdx.x;           // 0..63
    const int* ids = char_ids + idx * WP_;
    for (int i = t; i < WP_ * E_; i += 64) {
        int r = i >> 7, e = i & 127;
        ce[r * CE_S + e] = char_emb[ids[r] * E_ + e];
    }
    for (int i = t; i < L_ * K_ * E_; i += 64) {
        int r = i / (K_ * E_), e = i % (K_ * E_);
        w[r * W_S + e] = cnn_w[i];
    }
    if (t < L_) bias[t] = cnn_b[t];
    __syncthreads();
    int pos = t >> 2, c = t & 3;     // 16 positions x 4 channels
    float acc = 0.f;
    const float* wr = &w[c * W_S];
    #pragma unroll
    for (int i = 0; i < K_; ++i) {
        const float* cr = &ce[(pos + i) * CE_S];
        #pragma unroll 8
        for (int e = 0; e < E_; ++e) acc = fmaf(cr[e], wr[i * E_ + e], acc);
    }
    acc += bias[c];
    #pragma unroll
    for (int off = 4; off < 64; off <<= 1) acc = fmaxf(acc, __shfl_xor(acc, off));
    if (t < L_) out_char[idx * L_ + t] = acc;
}

// ---------------------------------------------------------------- input proj
// igq[row*1024 + i*4 + g] = b[g*256+i] + sum_k we[row,k]*WihT[k, g*256+i]
__global__ void k_input_proj(const int* __restrict__ word_ids,
                             const float* __restrict__ word_emb,
                             const bf16* __restrict__ wihT_f, const float* __restrict__ b_f,
                             const bf16* __restrict__ wihT_b, const float* __restrict__ b_b,
                             bf16* __restrict__ igq_f, bf16* __restrict__ igq_b) {
    int dir = blockIdx.y;
    const bf16* wihT = dir ? wihT_b : wihT_f;
    const float* bb  = dir ? b_b    : b_f;
    bf16* igq        = dir ? igq_b  : igq_f;
    __shared__ float x[8][128];
    int t  = threadIdx.x;            // 0..255 = unit i
    int r0 = blockIdx.x * 8;         // 8 rows (s*B+b) per block
    for (int i = t; i < 8 * 128; i += 256) {
        int rr = i >> 7, e = i & 127;
        int r = r0 + rr;
        int s = r >> 6, b = r & 63;
        int wid = word_ids[b * S_ + s];
        x[rr][e] = word_emb[(size_t)wid * E_ + e];
    }
    __syncthreads();
    int j = t;
    float acc[4][8];
    #pragma unroll
    for (int cj = 0; cj < 4; ++cj) {
        float bv = bb[j + cj * 256];
        #pragma unroll
        for (int rr = 0; rr < 8; ++rr) acc[cj][rr] = bv;
    }
    for (int k = 0; k < 128; ++k) {
        float wv[4];
        #pragma unroll
        for (int cj = 0; cj < 4; ++cj) wv[cj] = b2f(wihT[k * 1024 + j + cj * 256]);
        #pragma unroll
        for (int rr = 0; rr < 8; ++rr) {
            float xv = x[rr][k];
            #pragma unroll
            for (int cj = 0; cj < 4; ++cj) acc[cj][rr] = fmaf(xv, wv[cj], acc[cj][rr]);
        }
    }
    #pragma unroll
    for (int cj = 0; cj < 4; ++cj)
        #pragma unroll
        for (int rr = 0; rr < 8; ++rr)
            igq[(size_t)(r0 + rr) * 1024 + j * 4 + cj] = f2b(acc[cj][rr]);
}

// ---------------------------------------------------------------- recurrence (k-split + dot2)
// One block per (batch, direction). Thread t: unit i=t>>2, k-slice p=t&3.
// FIX vs round 8: only p==0 seeds z with the ig term (butterfly was summing it 4x).
__global__ __launch_bounds__(1024) void k_lstm_rec(
        const bf16* __restrict__ igq_f, const bf16* __restrict__ igq_b,
        const uint4* __restrict__ wp_f, const uint4* __restrict__ wp_b,
        float* __restrict__ hf, float* __restrict__ hb) {
    __shared__ uint4 wlds[9216];                    // 144 KiB, m = 0..8
    __shared__ __align__(16) unsigned int hpbuf[2][160];  // padded bf16-pair h, dbuf

    int b   = blockIdx.x & 63;
    int dir = blockIdx.x >> 6;
    const bf16* igq = dir ? igq_b : igq_f;
    const uint4* wp = dir ? wp_b  : wp_f;
    float* hs       = dir ? hb    : hf;

    int t = threadIdx.x;
    int i = t >> 2, p = t & 3;

    for (int u = t; u < 9216; u += 1024) wlds[u] = wp[u];
    if (t < 320) ((unsigned int*)hpbuf)[t] = 0;
    float c_reg = 0.f;
    __syncthreads();

    int cur = 0;
    int s0 = dir ? (S_ - 1) : 0;
    uint2 igu = *(const uint2*)&igq[((size_t)s0 * B_ + b) * 1024 + i * 4];

    for (int step = 0; step < S_; ++step) {
        int s = dir ? (S_ - 1 - step) : step;
        float z0 = 0.f, z1 = 0.f, z2 = 0.f, z3 = 0.f;
        if (p == 0) {                       // seed ig term exactly once
            z0 = __uint_as_float(igu.x << 16);
            z1 = __uint_as_float(igu.x & 0xffff0000u);
            z2 = __uint_as_float(igu.y << 16);
            z3 = __uint_as_float(igu.y & 0xffff0000u);
        }
        const char* hpc = (const char*)hpbuf[cur];
        #pragma unroll
        for (int kk = 0; kk < 8; ++kk) {
            uint4 hv = *(const uint4*)(hpc + p * 144 + kk * 16);
            {   // g = 0, m = kk (<9 -> LDS)
                uint4 wv = wlds[kk * 1024 + t];
                DOT2(z0, wv.x, hv.x); DOT2(z0, wv.y, hv.y);
                DOT2(z0, wv.z, hv.z); DOT2(z0, wv.w, hv.w);
            }
            {   // g = 1, m = 8+kk (8 -> LDS, else global)
                uint4 wv = (kk == 0) ? wlds[8 * 1024 + t] : wp[(8 + kk) * 1024 + t];
                DOT2(z1, wv.x, hv.x); DOT2(z1, wv.y, hv.y);
                DOT2(z1, wv.z, hv.z); DOT2(z1, wv.w, hv.w);
            }
            {   // g = 2, m = 16+kk (global)
                uint4 wv = wp[(16 + kk) * 1024 + t];
                DOT2(z2, wv.x, hv.x); DOT2(z2, wv.y, hv.y);
                DOT2(z2, wv.z, hv.z); DOT2(z2, wv.w, hv.w);
            }
            {   // g = 3, m = 24+kk (global)
                uint4 wv = wp[(24 + kk) * 1024 + t];
                DOT2(z3, wv.x, hv.x); DOT2(z3, wv.y, hv.y);
                DOT2(z3, wv.z, hv.z); DOT2(z3, wv.w, hv.w);
            }
        }
        // prefetch next step's ig quad (hides L2 latency under reduce/gates)
        if (step + 1 < S_) {
            int sn = dir ? (S_ - 2 - step) : (step + 1);
            igu = *(const uint2*)&igq[((size_t)sn * B_ + b) * 1024 + i * 4];
        }
        // butterfly sum across p (lanes differing in bits 0-1)
        z0 += __shfl_xor(z0, 1); z0 += __shfl_xor(z0, 2);
        z1 += __shfl_xor(z1, 1); z1 += __shfl_xor(z1, 2);
        z2 += __shfl_xor(z2, 1); z2 += __shfl_xor(z2, 2);
        z3 += __shfl_xor(z3, 1); z3 += __shfl_xor(z3, 2);
        if (p == 0) {
            float si = fast_sigmoid(z0);
            float sf = fast_sigmoid(z1);
            float tg = fast_tanh(z2);
            float so = fast_sigmoid(z3);
            c_reg = sf * c_reg + si * tg;
            float hn = so * fast_tanh(c_reg);
            hs[((size_t)s * B_ + b) * 256 + i] = hn;
            // store bf16 h into next buffer: seg (i>>6), pair (i>>1)&31, half (i&1)
            char* dstb = (char*)hpbuf[cur ^ 1] + (i >> 6) * 144 + ((i >> 1) & 31) * 4 + (i & 1) * 2;
            *(bf16*)dstb = f2b(hn);
        }
        __syncthreads();
        cur ^= 1;
    }
}

// ---------------------------------------------------------------- tag linear
__global__ void k_tag_linear(const float* __restrict__ hf, const float* __restrict__ hb,
                             const float* __restrict__ out_w, const float* __restrict__ out_b,
                             float* __restrict__ tag) {
    int bs = blockIdx.x;             // b*S + s
    int b = bs >> 7, s = bs & 127;
    __shared__ float hv[512];
    int t = threadIdx.x;             // 0..63
    const float* hfr = hf + ((size_t)s * B_ + b) * 256;
    const float* hbr = hb + ((size_t)s * B_ + b) * 256;
    for (int i = t; i < 256; i += 64) { hv[i] = hfr[i]; hv[256 + i] = hbr[i]; }
    __syncthreads();
    if (t < T_) {
        float acc = out_b[t];
        #pragma unroll 8
        for (int k = 0; k < 512; ++k) acc = fmaf(hv[k], out_w[t * 512 + k], acc);
        tag[((size_t)b * T_ + t) * S_ + s] = acc;
    }
}

// ---------------------------------------------------------------- log_softmax over S (axis=1)
__global__ void k_log_softmax(const float* __restrict__ tag, float* __restrict__ out) {
    int wid  = (blockIdx.x * 256 + threadIdx.x) >> 6;   // one wave per (b,t)
    int lane = threadIdx.x & 63;
    if (wid >= B_ * T_) return;
    int b = wid / T_, t = wid % T_;
    const float* row = tag + (size_t)wid * S_;
    float v0 = row[lane], v1 = row[lane + 64];
    float m = fmaxf(v0, v1);
    #pragma unroll
    for (int off = 32; off; off >>= 1) m = fmaxf(m, __shfl_xor(m, off));
    float e = expf(v0 - m) + expf(v1 - m);
    #pragma unroll
    for (int off = 32; off; off >>= 1) e += __shfl_xor(e, off);
    float lse = m + logf(e);
    out[((size_t)b * S_ + lane)      * T_ + t] = v0 - lse;
    out[((size_t)b * S_ + lane + 64) * T_ + t] = v1 - lse;
}

// ---------------------------------------------------------------- launch
extern "C" void kernel_launch(void* const* d_in, const int* in_sizes, int n_in,
                              void* d_out, int out_size, void* d_ws, size_t ws_size,
                              hipStream_t stream) {
    const int*   char_ids = (const int*)d_in[0];
    const int*   word_ids = (const int*)d_in[1];
    const float* char_emb = (const float*)d_in[2];
    const float* word_emb = (const float*)d_in[3];
    const float* cnn_w    = (const float*)d_in[4];
    const float* cnn_b    = (const float*)d_in[5];
    const float* wih_f    = (const float*)d_in[6];
    const float* whh_f    = (const float*)d_in[7];
    const float* b_f      = (const float*)d_in[8];
    const float* wih_b    = (const float*)d_in[9];
    const float* whh_b    = (const float*)d_in[10];
    const float* b_b      = (const float*)d_in[11];
    const float* out_w    = (const float*)d_in[12];
    const float* out_b    = (const float*)d_in[13];
    float* out = (float*)d_out;
    char* ws   = (char*)d_ws;

    size_t o = 0;
    bf16* wihT_f = (bf16*)(ws + o); o += (size_t)128 * 1024 * 2;
    bf16* wihT_b = (bf16*)(ws + o); o += (size_t)128 * 1024 * 2;
    bf16* wp_f   = (bf16*)(ws + o); o += (size_t)256 * 1024 * 2;
    bf16* wp_b   = (bf16*)(ws + o); o += (size_t)256 * 1024 * 2;
    bf16* igq_f  = (bf16*)(ws + o); o += (size_t)S_ * B_ * 1024 * 2;
    bf16* igq_b  = (bf16*)(ws + o); o += (size_t)S_ * B_ * 1024 * 2;
    float* hf    = (float*)(ws + o); o += (size_t)S_ * B_ * 256 * 4;
    float* hb    = (float*)(ws + o); o += (size_t)S_ * B_ * 256 * 4;
    float* tag   = (float*)(ws + o); o += (size_t)B_ * T_ * S_ * 4;

    k_transpose<<<512, 256, 0, stream>>>(wih_f, wihT_f, 1024, 128);
    k_transpose<<<512, 256, 0, stream>>>(wih_b, wihT_b, 1024, 128);
    k_pack_whh<<<1024, 256, 0, stream>>>(whh_f, wp_f);
    k_pack_whh<<<1024, 256, 0, stream>>>(whh_b, wp_b);
    k_input_proj<<<dim3(1024, 2), 256, 0, stream>>>(word_ids, word_emb,
                                                    wihT_f, b_f, wihT_b, b_b, igq_f, igq_b);
    k_charcnn<<<B_ * S_, 64, 0, stream>>>(char_ids, char_emb, cnn_w, cnn_b,
                                          out + (size_t)B_ * S_ * T_);
    k_lstm_rec<<<128, 1024, 0, stream>>>(igq_f, igq_b, (const uint4*)wp_f, (const uint4*)wp_b,
                                         hf, hb);
    k_tag_linear<<<B_ * S_, 64, 0, stream>>>(hf, hb, out_w, out_b, tag);
    k_log_softmax<<<(B_ * T_ + 3) / 4, 256, 0, stream>>>(tag, out);
}

// Round 10
// 492.230 us; speedup vs baseline: 6.9798x; 1.4977x over previous
//
#include <hip/hip_runtime.h>
#include <hip/hip_bf16.h>

#define B_  64
#define S_  128
#define WP_ 18
#define K_  3
#define E_  128
#define H_  256
#define L_  4
#define T_  50

typedef __hip_bfloat16 bf16;

__device__ __forceinline__ float b2f(bf16 x) { return __bfloat162float(x); }
__device__ __forceinline__ bf16  f2b(float x) { return __float2bfloat16(x); }

__device__ __forceinline__ float fast_sigmoid(float x) {
    return 1.f / (1.f + __expf(-x));
}
__device__ __forceinline__ float fast_tanh(float x) {
    float a = fminf(fmaxf(2.f * x, -30.f), 30.f);
    float e = __expf(a);
    return (e - 1.f) / (e + 1.f);
}

// v_dot2_f32_bf16: z += lo(w)*lo(h) + hi(w)*hi(h), all ops one VALU inst
#define DOT2(z, w, h) asm("v_dot2_f32_bf16 %0, %1, %2, %0" : "+v"(z) : "v"(w), "v"(h))

// ---------------------------------------------------------------- transpose (f32 -> bf16)
__global__ void k_transpose(const float* __restrict__ src, bf16* __restrict__ dst,
                            int R, int C) {
    int i = blockIdx.x * 256 + threadIdx.x;
    if (i >= R * C) return;
    int r = i / C, c = i % C;
    dst[c * R + r] = f2b(src[i]);
}

// ---------------------------------------------------------------- pack Whh for k-split layout
// thread (i,p) [t=i*4+p] needs w[col=g*256+i][k=64p..64p+63] as 8 uint4 (m=g*8+kk).
// dst uint4 index = m*1024 + t; bf16 element e = k&7.
__global__ void k_pack_whh(const float* __restrict__ src, bf16* __restrict__ dst) {
    int idx = blockIdx.x * 256 + threadIdx.x;   // over 1024*256
    if (idx >= 1024 * 256) return;
    int col = idx >> 8, k = idx & 255;
    int g = col >> 8, i = col & 255;
    int p = k >> 6, kk = (k >> 3) & 7, e = k & 7;
    int t = i * 4 + p, m = g * 8 + kk;
    dst[((size_t)(m * 1024 + t) << 3) + e] = f2b(src[col * 256 + k]);
}

// ---------------------------------------------------------------- char CNN
__global__ void k_charcnn(const int* __restrict__ char_ids,
                          const float* __restrict__ char_emb,
                          const float* __restrict__ cnn_w,
                          const float* __restrict__ cnn_b,
                          float* __restrict__ out_char) {
    const int CE_S = 132;
    const int W_S  = 388;
    __shared__ float ce[WP_ * 132];
    __shared__ float w[L_ * 388];
    __shared__ float bias[L_];
    int idx = blockIdx.x;            // b*S + s
    int t   = threadIdx.x;           // 0..63
    const int* ids = char_ids + idx * WP_;
    for (int i = t; i < WP_ * E_; i += 64) {
        int r = i >> 7, e = i & 127;
        ce[r * CE_S + e] = char_emb[ids[r] * E_ + e];
    }
    for (int i = t; i < L_ * K_ * E_; i += 64) {
        int r = i / (K_ * E_), e = i % (K_ * E_);
        w[r * W_S + e] = cnn_w[i];
    }
    if (t < L_) bias[t] = cnn_b[t];
    __syncthreads();
    int pos = t >> 2, c = t & 3;     // 16 positions x 4 channels
    float acc = 0.f;
    const float* wr = &w[c * W_S];
    #pragma unroll
    for (int i = 0; i < K_; ++i) {
        const float* cr = &ce[(pos + i) * CE_S];
        #pragma unroll 8
        for (int e = 0; e < E_; ++e) acc = fmaf(cr[e], wr[i * E_ + e], acc);
    }
    acc += bias[c];
    #pragma unroll
    for (int off = 4; off < 64; off <<= 1) acc = fmaxf(acc, __shfl_xor(acc, off));
    if (t < L_) out_char[idx * L_ + t] = acc;
}

// ---------------------------------------------------------------- input proj
// igq[row*1024 + i*4 + g] = b[g*256+i] + sum_k we[row,k]*WihT[k, g*256+i]
__global__ void k_input_proj(const int* __restrict__ word_ids,
                             const float* __restrict__ word_emb,
                             const bf16* __restrict__ wihT_f, const float* __restrict__ b_f,
                             const bf16* __restrict__ wihT_b, const float* __restrict__ b_b,
                             bf16* __restrict__ igq_f, bf16* __restrict__ igq_b) {
    int dir = blockIdx.y;
    const bf16* wihT = dir ? wihT_b : wihT_f;
    const float* bb  = dir ? b_b    : b_f;
    bf16* igq        = dir ? igq_b  : igq_f;
    __shared__ float x[8][128];
    int t  = threadIdx.x;            // 0..255 = unit i
    int r0 = blockIdx.x * 8;         // 8 rows (s*B+b) per block
    for (int i = t; i < 8 * 128; i += 256) {
        int rr = i >> 7, e = i & 127;
        int r = r0 + rr;
        int s = r >> 6, b = r & 63;
        int wid = word_ids[b * S_ + s];
        x[rr][e] = word_emb[(size_t)wid * E_ + e];
    }
    __syncthreads();
    int j = t;
    float acc[4][8];
    #pragma unroll
    for (int cj = 0; cj < 4; ++cj) {
        float bv = bb[j + cj * 256];
        #pragma unroll
        for (int rr = 0; rr < 8; ++rr) acc[cj][rr] = bv;
    }
    for (int k = 0; k < 128; ++k) {
        float wv[4];
        #pragma unroll
        for (int cj = 0; cj < 4; ++cj) wv[cj] = b2f(wihT[k * 1024 + j + cj * 256]);
        #pragma unroll
        for (int rr = 0; rr < 8; ++rr) {
            float xv = x[rr][k];
            #pragma unroll
            for (int cj = 0; cj < 4; ++cj) acc[cj][rr] = fmaf(xv, wv[cj], acc[cj][rr]);
        }
    }
    #pragma unroll
    for (int cj = 0; cj < 4; ++cj)
        #pragma unroll
        for (int rr = 0; rr < 8; ++rr)
            igq[(size_t)(r0 + rr) * 1024 + j * 4 + cj] = f2b(acc[cj][rr]);
}

// ---------------------------------------------------------------- recurrence (k-split + dot2)
// One block per (batch, direction). Thread t: unit i=t>>2, k-slice p=t&3.
// Three-tier weights: m=0..8 in registers (36 VGPR, persistent),
// m=9..17 in LDS (144 KB), m=18..31 streamed from L2 with all loads
// issued upfront per step (MLP).
__global__ __launch_bounds__(1024) void k_lstm_rec(
        const bf16* __restrict__ igq_f, const bf16* __restrict__ igq_b,
        const uint4* __restrict__ wp_f, const uint4* __restrict__ wp_b,
        float* __restrict__ hf, float* __restrict__ hb) {
    __shared__ uint4 wlds[9216];                    // 144 KiB, m = 9..17
    __shared__ __align__(16) unsigned int hpbuf[2][160];  // padded bf16-pair h, dbuf

    int b   = blockIdx.x & 63;
    int dir = blockIdx.x >> 6;
    const bf16* igq = dir ? igq_b : igq_f;
    const uint4* wp = dir ? wp_b  : wp_f;
    float* hs       = dir ? hb    : hf;

    int t = threadIdx.x;
    int i = t >> 2, p = t & 3;

    for (int u = t; u < 9216; u += 1024) wlds[u] = wp[9 * 1024 + u];
    if (t < 320) ((unsigned int*)hpbuf)[t] = 0;
    float c_reg = 0.f;

    // register tier: m = 0..8 (persistent, compile-time indexed after unroll)
    uint4 wreg[9];
    #pragma unroll
    for (int m = 0; m < 9; ++m) wreg[m] = wp[m * 1024 + t];
    __syncthreads();

    int cur = 0;
    int s0 = dir ? (S_ - 1) : 0;
    uint2 igu = *(const uint2*)&igq[((size_t)s0 * B_ + b) * 1024 + i * 4];

    for (int step = 0; step < S_; ++step) {
        int s = dir ? (S_ - 1 - step) : step;

        // issue ALL 14 streamed weight loads upfront (g2 kk=2..7, g3 kk=0..7)
        uint4 ga[6], gb[8];
        #pragma unroll
        for (int u = 0; u < 6; ++u) ga[u] = wp[(18 + u) * 1024 + t];
        #pragma unroll
        for (int u = 0; u < 8; ++u) gb[u] = wp[(24 + u) * 1024 + t];

        float z0 = 0.f, z1 = 0.f, z2 = 0.f, z3 = 0.f;
        if (p == 0) {                       // seed ig term exactly once
            z0 = __uint_as_float(igu.x << 16);
            z1 = __uint_as_float(igu.x & 0xffff0000u);
            z2 = __uint_as_float(igu.y << 16);
            z3 = __uint_as_float(igu.y & 0xffff0000u);
        }
        const char* hpc = (const char*)hpbuf[cur];
        #pragma unroll
        for (int kk = 0; kk < 8; ++kk) {
            uint4 hv = *(const uint4*)(hpc + p * 144 + kk * 16);
            {   // g = 0, m = kk  -> registers
                uint4 wv = wreg[kk];
                DOT2(z0, wv.x, hv.x); DOT2(z0, wv.y, hv.y);
                DOT2(z0, wv.z, hv.z); DOT2(z0, wv.w, hv.w);
            }
            {   // g = 1, m = 8+kk -> kk==0: reg; else LDS (m=9..15)
                uint4 wv = (kk == 0) ? wreg[8] : wlds[(kk - 1) * 1024 + t];
                DOT2(z1, wv.x, hv.x); DOT2(z1, wv.y, hv.y);
                DOT2(z1, wv.z, hv.z); DOT2(z1, wv.w, hv.w);
            }
            {   // g = 2, m = 16+kk -> kk<2: LDS (m=16,17); else streamed
                uint4 wv = (kk < 2) ? wlds[(7 + kk) * 1024 + t] : ga[kk - 2];
                DOT2(z2, wv.x, hv.x); DOT2(z2, wv.y, hv.y);
                DOT2(z2, wv.z, hv.z); DOT2(z2, wv.w, hv.w);
            }
            {   // g = 3, m = 24+kk -> streamed
                uint4 wv = gb[kk];
                DOT2(z3, wv.x, hv.x); DOT2(z3, wv.y, hv.y);
                DOT2(z3, wv.z, hv.z); DOT2(z3, wv.w, hv.w);
            }
        }
        // prefetch next step's ig quad (hides L2 latency under reduce/gates)
        if (step + 1 < S_) {
            int sn = dir ? (S_ - 2 - step) : (step + 1);
            igu = *(const uint2*)&igq[((size_t)sn * B_ + b) * 1024 + i * 4];
        }
        // butterfly sum across p (lanes differing in bits 0-1)
        z0 += __shfl_xor(z0, 1); z0 += __shfl_xor(z0, 2);
        z1 += __shfl_xor(z1, 1); z1 += __shfl_xor(z1, 2);
        z2 += __shfl_xor(z2, 1); z2 += __shfl_xor(z2, 2);
        z3 += __shfl_xor(z3, 1); z3 += __shfl_xor(z3, 2);
        if (p == 0) {
            float si = fast_sigmoid(z0);
            float sf = fast_sigmoid(z1);
            float tg = fast_tanh(z2);
            float so = fast_sigmoid(z3);
            c_reg = sf * c_reg + si * tg;
            float hn = so * fast_tanh(c_reg);
            hs[((size_t)s * B_ + b) * 256 + i] = hn;
            // store bf16 h into next buffer: seg (i>>6), pair (i>>1)&31, half (i&1)
            char* dstb = (char*)hpbuf[cur ^ 1] + (i >> 6) * 144 + ((i >> 1) & 31) * 4 + (i & 1) * 2;
            *(bf16*)dstb = f2b(hn);
        }
        __syncthreads();
        cur ^= 1;
    }
}

// ---------------------------------------------------------------- tag linear
__global__ void k_tag_linear(const float* __restrict__ hf, const float* __restrict__ hb,
                             const float* __restrict__ out_w, const float* __restrict__ out_b,
                             float* __restrict__ tag) {
    int bs = blockIdx.x;             // b*S + s
    int b = bs >> 7, s = bs & 127;
    __shared__ float hv[512];
    int t = threadIdx.x;             // 0..63
    const float* hfr = hf + ((size_t)s * B_ + b) * 256;
    const float* hbr = hb + ((size_t)s * B_ + b) * 256;
    for (int i = t; i < 256; i += 64) { hv[i] = hfr[i]; hv[256 + i] = hbr[i]; }
    __syncthreads();
    if (t < T_) {
        float acc = out_b[t];
        #pragma unroll 8
        for (int k = 0; k < 512; ++k) acc = fmaf(hv[k], out_w[t * 512 + k], acc);
        tag[((size_t)b * T_ + t) * S_ + s] = acc;
    }
}

// ---------------------------------------------------------------- log_softmax over S (axis=1)
__global__ void k_log_softmax(const float* __restrict__ tag, float* __restrict__ out) {
    int wid  = (blockIdx.x * 256 + threadIdx.x) >> 6;   // one wave per (b,t)
    int lane = threadIdx.x & 63;
    if (wid >= B_ * T_) return;
    int b = wid / T_, t = wid % T_;
    const float* row = tag + (size_t)wid * S_;
    float v0 = row[lane], v1 = row[lane + 64];
    float m = fmaxf(v0, v1);
    #pragma unroll
    for (int off = 32; off; off >>= 1) m = fmaxf(m, __shfl_xor(m, off));
    float e = expf(v0 - m) + expf(v1 - m);
    #pragma unroll
    for (int off = 32; off; off >>= 1) e += __shfl_xor(e, off);
    float lse = m + logf(e);
    out[((size_t)b * S_ + lane)      * T_ + t] = v0 - lse;
    out[((size_t)b * S_ + lane + 64) * T_ + t] = v1 - lse;
}

// ---------------------------------------------------------------- launch
extern "C" void kernel_launch(void* const* d_in, const int* in_sizes, int n_in,
                              void* d_out, int out_size, void* d_ws, size_t ws_size,
                              hipStream_t stream) {
    const int*   char_ids = (const int*)d_in[0];
    const int*   word_ids = (const int*)d_in[1];
    const float* char_emb = (const float*)d_in[2];
    const float* word_emb = (const float*)d_in[3];
    const float* cnn_w    = (const float*)d_in[4];
    const float* cnn_b    = (const float*)d_in[5];
    const float* wih_f    = (const float*)d_in[6];
    const float* whh_f    = (const float*)d_in[7];
    const float* b_f      = (const float*)d_in[8];
    const float* wih_b    = (const float*)d_in[9];
    const float* whh_b    = (const float*)d_in[10];
    const float* b_b      = (const float*)d_in[11];
    const float* out_w    = (const float*)d_in[12];
    const float* out_b    = (const float*)d_in[13];
    float* out = (float*)d_out;
    char* ws   = (char*)d_ws;

    size_t o = 0;
    bf16* wihT_f = (bf16*)(ws + o); o += (size_t)128 * 1024 * 2;
    bf16* wihT_b = (bf16*)(ws + o); o += (size_t)128 * 1024 * 2;
    bf16* wp_f   = (bf16*)(ws + o); o += (size_t)256 * 1024 * 2;
    bf16* wp_b   = (bf16*)(ws + o); o += (size_t)256 * 1024 * 2;
    bf16* igq_f  = (bf16*)(ws + o); o += (size_t)S_ * B_ * 1024 * 2;
    bf16* igq_b  = (bf16*)(ws + o); o += (size_t)S_ * B_ * 1024 * 2;
    float* hf    = (float*)(ws + o); o += (size_t)S_ * B_ * 256 * 4;
    float* hb    = (float*)(ws + o); o += (size_t)S_ * B_ * 256 * 4;
    float* tag   = (float*)(ws + o); o += (size_t)B_ * T_ * S_ * 4;

    k_transpose<<<512, 256, 0, stream>>>(wih_f, wihT_f, 1024, 128);
    k_transpose<<<512, 256, 0, stream>>>(wih_b, wihT_b, 1024, 128);
    k_pack_whh<<<1024, 256, 0, stream>>>(whh_f, wp_f);
    k_pack_whh<<<1024, 256, 0, stream>>>(whh_b, wp_b);
    k_input_proj<<<dim3(1024, 2), 256, 0, stream>>>(word_ids, word_emb,
                                                    wihT_f, b_f, wihT_b, b_b, igq_f, igq_b);
    k_charcnn<<<B_ * S_, 64, 0, stream>>>(char_ids, char_emb, cnn_w, cnn_b,
                                          out + (size_t)B_ * S_ * T_);
    k_lstm_rec<<<128, 1024, 0, stream>>>(igq_f, igq_b, (const uint4*)wp_f, (const uint4*)wp_b,
                                         hf, hb);
    k_tag_linear<<<B_ * S_, 64, 0, stream>>>(hf, hb, out_w, out_b, tag);
    k_log_softmax<<<(B_ * T_ + 3) / 4, 256, 0, stream>>>(tag, out);
}